// Round 1
// baseline (331.922 us; speedup 1.0000x reference)
//
#include <hip/hip_runtime.h>
#include <cstdint>
#include <cstddef>

// Problem constants (from reference): N=16384, D=256. max_deg derived at runtime.
#define NV 16384
#define DD 256
#define BLK 1024

// ---------------------------------------------------------------------------
// K1: lexicographic greedy MIS (= head_mask of the sequential scan), single WG.
// Processes vertices in 16 sequential blocks of 1024; within a block, Jacobi
// micro-rounds until all decided. Status in LDS: 0=unknown, 1=head, 2=nonhead.
// Monotone byte writes -> intra-round read/write races are benign (a read sees
// 0 or the final value; decisions only trigger on final values).
// Then prefix-sums head ranks, writes rank[v] (or -1), head_mask floats, and
// num_clusters.
// ---------------------------------------------------------------------------
__global__ __launch_bounds__(1024)
void k_mis(const int* __restrict__ nbr, const int* __restrict__ deg,
           int maxdeg, int n,
           int* __restrict__ g_rank, float* __restrict__ out_tail)
{
    __shared__ unsigned char st[NV];
    __shared__ int s_scan[1024];
    const int t = threadIdx.x;

    for (int i = t; i < n; i += 1024) st[i] = 0;
    __syncthreads();

    for (int b = 0; b < n; b += BLK) {
        const int v  = b + t;
        const int dv = (v < n) ? deg[v] : 0;
        const int* __restrict__ row = nbr + (size_t)v * (size_t)maxdeg;
        int my = (v < n) ? 0 : 2;
        for (;;) {
            if (my == 0) {
                bool anyHead = false, allNH = true;
                for (int k = 0; k < dv; ++k) {
                    int j = row[k];           // independent loads, no early break
                    if (j < v) {
                        unsigned char s = st[j];
                        anyHead = anyHead || (s == 1);
                        allNH   = allNH   && (s == 2);
                    }
                }
                if (anyHead)    my = 2;       // some lower head neighbor -> absorbed
                else if (allNH) my = 1;       // all lower neighbors final non-heads -> head
                if (my) st[v] = (unsigned char)my;
            }
            if (__syncthreads_count(my == 0) == 0) break;
        }
    }

    // ---- head rank prefix sum (index order) ----
    const int per  = n / 1024;          // 16
    const int base = t * per;
    int cnt = 0;
    for (int i = 0; i < per; ++i) cnt += (st[base + i] == 1) ? 1 : 0;
    s_scan[t] = cnt;
    __syncthreads();
    for (int off = 1; off < 1024; off <<= 1) {
        int x = (t >= off) ? s_scan[t - off] : 0;
        __syncthreads();
        s_scan[t] += x;
        __syncthreads();
    }
    int excl  = s_scan[t] - cnt;        // exclusive scan value for this chunk
    int total = s_scan[1023];

    for (int i = 0; i < per; ++i) {
        int v = base + i;
        bool h = (st[v] == 1);
        g_rank[v]   = h ? excl : -1;
        if (h) excl++;
        out_tail[v] = h ? 1.0f : 0.0f;  // head_mask as floats
    }
    if (t == 0) out_tail[n] = (float)total;   // num_clusters as float
}

// ---------------------------------------------------------------------------
// K2: owner[v] = v if head, else min-index head neighbor (always exists, < v).
// ---------------------------------------------------------------------------
__global__ __launch_bounds__(256)
void k_owner(const int* __restrict__ nbr, const int* __restrict__ deg,
             int maxdeg, int n,
             const int* __restrict__ g_rank, int* __restrict__ owner)
{
    int v = blockIdx.x * 256 + threadIdx.x;
    if (v >= n) return;
    if (g_rank[v] >= 0) { owner[v] = v; return; }
    const int* __restrict__ row = nbr + (size_t)v * (size_t)maxdeg;
    const int dv = deg[v];
    int mn = 0x7fffffff;
    for (int k = 0; k < dv; ++k) {
        int j = row[k];
        if (g_rank[j] >= 0 && j < mn) mn = j;
    }
    owner[v] = mn;
}

// ---------------------------------------------------------------------------
// K3: one 64-lane wave per vertex; head waves compute the cluster mean.
// Members of head h = {h} U { j in nbr[h] : owner[j] == h }  (heads only absorb
// higher-index neighbors from their own adjacency row).
// Row layout: 256 floats = 64 lanes x float4, fully coalesced per row.
// ---------------------------------------------------------------------------
__global__ __launch_bounds__(256)
void k_avg(const float* __restrict__ vert, const int* __restrict__ nbr,
           const int* __restrict__ deg, int maxdeg, int n,
           const int* __restrict__ g_rank, const int* __restrict__ owner,
           float* __restrict__ out)
{
    const int wid  = (blockIdx.x * 256 + threadIdx.x) >> 6;
    const int lane = threadIdx.x & 63;
    if (wid >= n) return;
    const int h = wid;
    const int c = g_rank[h];
    if (c < 0) return;                       // not a head

    const int dh = deg[h];
    const int* __restrict__ row = nbr + (size_t)h * (size_t)maxdeg;

    float4 acc = reinterpret_cast<const float4*>(vert + (size_t)h * DD)[lane];
    int cnt = 1;

    for (int k0 = 0; k0 < dh; k0 += 64) {
        int k = k0 + lane;
        int j = (k < dh) ? row[k] : -1;
        bool mem = (j >= 0) && (owner[j] == h);
        unsigned long long m = __ballot(mem);
        cnt += __popcll(m);
        while (m) {
            int b = __ffsll((long long)m) - 1;
            m &= (m - 1);
            int jj = __shfl(j, b);
            float4 r = reinterpret_cast<const float4*>(vert + (size_t)jj * DD)[lane];
            acc.x += r.x; acc.y += r.y; acc.z += r.z; acc.w += r.w;
        }
    }
    const float inv = 1.0f / (float)cnt;
    float4 res;
    res.x = acc.x * inv; res.y = acc.y * inv;
    res.z = acc.z * inv; res.w = acc.w * inv;
    reinterpret_cast<float4*>(out + (size_t)c * DD)[lane] = res;
}

// ---------------------------------------------------------------------------
extern "C" void kernel_launch(void* const* d_in, const int* in_sizes, int n_in,
                              void* d_out, int out_size, void* d_ws, size_t ws_size,
                              hipStream_t stream)
{
    const float* vert = (const float*)d_in[0];
    const int*   nbr  = (const int*)d_in[1];
    const int*   deg  = (const int*)d_in[2];

    const int n      = in_sizes[2];            // 16384
    const int maxdeg = in_sizes[1] / n;
    const int d      = in_sizes[0] / n;        // 256

    int* owner = (int*)d_ws;                   // n ints
    int* rank  = owner + n;                    // n ints
    float* out      = (float*)d_out;
    float* out_tail = out + (size_t)n * (size_t)d;   // head_mask .. num_clusters

    // rows >= num_clusters must be zero; also covers the tail before K1 writes it
    hipMemsetAsync(d_out, 0, (size_t)out_size * sizeof(float), stream);

    hipLaunchKernelGGL(k_mis, dim3(1), dim3(1024), 0, stream,
                       nbr, deg, maxdeg, n, rank, out_tail);

    hipLaunchKernelGGL(k_owner, dim3((n + 255) / 256), dim3(256), 0, stream,
                       nbr, deg, maxdeg, n, rank, owner);

    const int blocks = (n * 64 + 255) / 256;   // one wave per vertex
    hipLaunchKernelGGL(k_avg, dim3(blocks), dim3(256), 0, stream,
                       vert, nbr, deg, maxdeg, n, rank, owner, out);
}

// Round 2
// 243.146 us; speedup vs baseline: 1.3651x; 1.3651x over previous
//
#include <hip/hip_runtime.h>
#include <cstdint>
#include <cstddef>

// Problem constants (from reference): N=16384, D=256. max_deg derived at runtime.
#define NV 16384
#define DD 256
#define BLK 1024
#define PENDCAP 16

// ---------------------------------------------------------------------------
// K1: lexicographic greedy MIS (= head_mask of the sequential scan), single WG.
// Processes vertices in 16 sequential blocks of 1024. For each vertex:
//   - ONE pass over its nbr row at block start: fold anyHead over already-
//     decided lower neighbors (j < b); collect in-block lower neighbors
//     (b <= j < v) into an LDS pending list (these are the only undecided ones).
//   - Jacobi micro-rounds touch ONLY the pending list (LDS), compacting it.
// Status in LDS: 0=unknown, 1=head, 2=nonhead. Monotone writes -> races benign.
// Overflow fallback (pending > PENDCAP, ~impossible): rescan global row.
// ---------------------------------------------------------------------------
__global__ __launch_bounds__(1024)
void k_mis(const int* __restrict__ nbr, const int* __restrict__ deg,
           int maxdeg, int n,
           int* __restrict__ g_rank, float* __restrict__ out_tail)
{
    __shared__ unsigned char st[NV];
    __shared__ unsigned short pend[PENDCAP * 1024];  // [slot][tid] - conflict-free
    __shared__ int s_scan[1024];
    const int t = threadIdx.x;

    for (int i = t; i < n; i += 1024) st[i] = 0;
    __syncthreads();

    for (int b = 0; b < n; b += BLK) {
        const int v  = b + t;
        const int dv = (v < n) ? deg[v] : 0;
        const int* __restrict__ row = nbr + (size_t)v * (size_t)maxdeg;
        int  my = (v < n) ? 0 : 2;
        int  np = 0;
        bool ovf = false;
        bool anyHead = false;

        // one-pass row scan: decided lower nbrs fold into anyHead;
        // in-block lower nbrs -> pending list
        for (int k = 0; k < dv; ++k) {
            int j = row[k];
            if (j >= v) continue;
            if (j >= b) {
                if (np < PENDCAP) pend[np * 1024 + t] = (unsigned short)(j - b);
                else ovf = true;
                ++np;
            } else {
                anyHead = anyHead || (st[j] == 1);
            }
        }
        if (my == 0) {
            if (anyHead)      my = 2;
            else if (np == 0) my = 1;
            if (my) st[v] = (unsigned char)my;
        }

        // micro-rounds over pending only (LDS traffic only)
        for (;;) {
            if (__syncthreads_count(my == 0) == 0) break;
            if (my == 0) {
                if (!ovf) {
                    int w = 0;
                    for (int i = 0; i < np; ++i) {
                        int jb = pend[i * 1024 + t];
                        unsigned char s = st[b + jb];
                        if (s == 1) anyHead = true;
                        else if (s == 0) { pend[w * 1024 + t] = (unsigned short)jb; ++w; }
                    }
                    np = w;
                } else {
                    // rare fallback: rescan global row for in-block lower nbrs
                    bool any0 = false;
                    for (int k = 0; k < dv; ++k) {
                        int j = row[k];
                        if (j >= v || j < b) continue;
                        unsigned char s = st[j];
                        if (s == 1) anyHead = true;
                        else if (s == 0) any0 = true;
                    }
                    np = any0 ? 1 : 0;
                }
                if (anyHead)      my = 2;
                else if (np == 0) my = 1;
                if (my) st[v] = (unsigned char)my;
            }
        }
    }

    // ---- head rank prefix sum (index order) ----
    const int per  = n / 1024;          // 16
    const int base = t * per;
    int cnt = 0;
    for (int i = 0; i < per; ++i) cnt += (st[base + i] == 1) ? 1 : 0;
    s_scan[t] = cnt;
    __syncthreads();
    for (int off = 1; off < 1024; off <<= 1) {
        int x = (t >= off) ? s_scan[t - off] : 0;
        __syncthreads();
        s_scan[t] += x;
        __syncthreads();
    }
    int excl  = s_scan[t] - cnt;        // exclusive scan value for this chunk
    int total = s_scan[1023];

    for (int i = 0; i < per; ++i) {
        int v = base + i;
        bool h = (st[v] == 1);
        g_rank[v]   = h ? excl : -1;
        if (h) excl++;
        out_tail[v] = h ? 1.0f : 0.0f;  // head_mask as floats
    }
    if (t == 0) out_tail[n] = (float)total;   // num_clusters as float
}

// ---------------------------------------------------------------------------
// K2: owner[v] = v if head, else min-index head neighbor (always exists, < v).
// ---------------------------------------------------------------------------
__global__ __launch_bounds__(256)
void k_owner(const int* __restrict__ nbr, const int* __restrict__ deg,
             int maxdeg, int n,
             const int* __restrict__ g_rank, int* __restrict__ owner)
{
    int v = blockIdx.x * 256 + threadIdx.x;
    if (v >= n) return;
    if (g_rank[v] >= 0) { owner[v] = v; return; }
    const int* __restrict__ row = nbr + (size_t)v * (size_t)maxdeg;
    const int dv = deg[v];
    int mn = 0x7fffffff;
    for (int k = 0; k < dv; ++k) {
        int j = row[k];
        if (g_rank[j] >= 0 && j < mn) mn = j;
    }
    owner[v] = mn;
}

// ---------------------------------------------------------------------------
// K3: one 64-lane wave per vertex; head waves compute the cluster mean.
// Members of head h = {h} U { j in nbr[h] : owner[j] == h }.
// Row layout: 256 floats = 64 lanes x float4, fully coalesced per row.
// ---------------------------------------------------------------------------
__global__ __launch_bounds__(256)
void k_avg(const float* __restrict__ vert, const int* __restrict__ nbr,
           const int* __restrict__ deg, int maxdeg, int n,
           const int* __restrict__ g_rank, const int* __restrict__ owner,
           float* __restrict__ out)
{
    const int wid  = (blockIdx.x * 256 + threadIdx.x) >> 6;
    const int lane = threadIdx.x & 63;
    if (wid >= n) return;
    const int h = wid;
    const int c = g_rank[h];
    if (c < 0) return;                       // not a head

    const int dh = deg[h];
    const int* __restrict__ row = nbr + (size_t)h * (size_t)maxdeg;

    float4 acc = reinterpret_cast<const float4*>(vert + (size_t)h * DD)[lane];
    int cnt = 1;

    for (int k0 = 0; k0 < dh; k0 += 64) {
        int k = k0 + lane;
        int j = (k < dh) ? row[k] : -1;
        bool mem = (j >= 0) && (owner[j] == h);
        unsigned long long m = __ballot(mem);
        cnt += __popcll(m);
        while (m) {
            int b = __ffsll((long long)m) - 1;
            m &= (m - 1);
            int jj = __shfl(j, b);
            float4 r = reinterpret_cast<const float4*>(vert + (size_t)jj * DD)[lane];
            acc.x += r.x; acc.y += r.y; acc.z += r.z; acc.w += r.w;
        }
    }
    const float inv = 1.0f / (float)cnt;
    float4 res;
    res.x = acc.x * inv; res.y = acc.y * inv;
    res.z = acc.z * inv; res.w = acc.w * inv;
    reinterpret_cast<float4*>(out + (size_t)c * DD)[lane] = res;
}

// ---------------------------------------------------------------------------
extern "C" void kernel_launch(void* const* d_in, const int* in_sizes, int n_in,
                              void* d_out, int out_size, void* d_ws, size_t ws_size,
                              hipStream_t stream)
{
    const float* vert = (const float*)d_in[0];
    const int*   nbr  = (const int*)d_in[1];
    const int*   deg  = (const int*)d_in[2];

    const int n      = in_sizes[2];            // 16384
    const int maxdeg = in_sizes[1] / n;
    const int d      = in_sizes[0] / n;        // 256

    int* owner = (int*)d_ws;                   // n ints
    int* rank  = owner + n;                    // n ints
    float* out      = (float*)d_out;
    float* out_tail = out + (size_t)n * (size_t)d;   // head_mask .. num_clusters

    // rows >= num_clusters must be zero; also covers the tail before K1 writes it
    hipMemsetAsync(d_out, 0, (size_t)out_size * sizeof(float), stream);

    hipLaunchKernelGGL(k_mis, dim3(1), dim3(1024), 0, stream,
                       nbr, deg, maxdeg, n, rank, out_tail);

    hipLaunchKernelGGL(k_owner, dim3((n + 255) / 256), dim3(256), 0, stream,
                       nbr, deg, maxdeg, n, rank, owner);

    const int blocks = (n * 64 + 255) / 256;   // one wave per vertex
    hipLaunchKernelGGL(k_avg, dim3(blocks), dim3(256), 0, stream,
                       vert, nbr, deg, maxdeg, n, rank, owner, out);
}

// Round 3
// 139.210 us; speedup vs baseline: 2.3843x; 1.7466x over previous
//
#include <hip/hip_runtime.h>
#include <cstdint>
#include <cstddef>

// Problem constants (from reference): N=16384, D=256. max_deg derived at runtime.
#define NV 16384
#define DD 256
#define BLK 1024
#define PCAP 7

// ---------------------------------------------------------------------------
// K_prep (parallel): for each vertex v, collect its in-block lower neighbors
// (j in [blockbase(v), v)) as u16 offsets, packed into one uint4:
//   x = count | e0<<16 ; y = e1|e2<<16 ; z = e3|e4<<16 ; w = e5|e6<<16
// These are the ONLY undecided lower neighbors when v's block is processed.
// ---------------------------------------------------------------------------
__global__ __launch_bounds__(256)
void k_prep(const int* __restrict__ nbr, const int* __restrict__ deg,
            int maxdeg, int n, uint4* __restrict__ pend_g)
{
    int v = blockIdx.x * 256 + threadIdx.x;
    if (v >= n) return;
    const int b  = v & ~(BLK - 1);
    const int dv = deg[v];
    const int* __restrict__ row = nbr + (size_t)v * (size_t)maxdeg;
    unsigned w0 = 0, w1 = 0, w2 = 0, w3 = 0;
    int cnt = 0;
    for (int k = 0; k < dv; ++k) {
        int j = row[k];
        if (j >= b && j < v) {
            unsigned val = (unsigned)(j - b);
            switch (cnt) {
                case 0: w0 |= val << 16; break;
                case 1: w1 |= val;       break;
                case 2: w1 |= val << 16; break;
                case 3: w2 |= val;       break;
                case 4: w2 |= val << 16; break;
                case 5: w3 |= val;       break;
                case 6: w3 |= val << 16; break;
                default: break;
            }
            ++cnt;
        }
    }
    w0 |= (unsigned)(cnt > 0xffff ? 0xffff : cnt);
    uint4 p; p.x = w0; p.y = w1; p.z = w2; p.w = w3;
    pend_g[v] = p;
}

// ---------------------------------------------------------------------------
// K_mis: lexicographic greedy MIS, single WG, PUSH model.
// st: 0=unknown, 1=head, 2=nonhead (monotone -> races benign).
// A head pushes st=2 to ALL higher neighbors (they are provably non-heads).
// So a vertex v is head iff st[v]==0 once all its in-block lower neighbors
// (the register-resident pending list) are decided. No pull over prev blocks.
// Rounds use one barrier each via a 3-slot rotating LDS flag.
// ---------------------------------------------------------------------------
__global__ __launch_bounds__(1024)
void k_mis(const int* __restrict__ nbr, const int* __restrict__ deg,
           int maxdeg, int n, const uint4* __restrict__ pend_g,
           int* __restrict__ g_rank, float* __restrict__ out_tail)
{
    __shared__ unsigned char st[NV];
    __shared__ int s_ws[16];
    __shared__ int F[3];
    const int t    = threadIdx.x;
    const int lane = t & 63;
    const int wid  = t >> 6;

    for (int i = t; i < NV; i += 1024) st[i] = 0;
    if (t < 3) F[t] = 0;
    __syncthreads();

    // prefetch block 0
    uint4 pv = (t < n) ? pend_g[t] : make_uint4(0, 0, 0, 0);
    int   dv = (t < n) ? deg[t] : 0;
    int   r  = 0;   // global round counter (for the 3-slot flag protocol)

    for (int b = 0; b < n; b += BLK) {
        const int v = b + t;
        // prefetch next block while this one iterates
        uint4 pnx = make_uint4(0, 0, 0, 0);
        int   dnx = 0;
        if (b + BLK < n) { pnx = pend_g[b + BLK + t]; dnx = deg[b + BLK + t]; }

        const int np = pv.x & 0xffff;
        const int e0 = pv.x >> 16,      e1 = pv.y & 0xffff, e2 = pv.y >> 16;
        const int e3 = pv.z & 0xffff,   e4 = pv.z >> 16;
        const int e5 = pv.w & 0xffff,   e6 = pv.w >> 16;
        const bool ovf = (np > PCAP);
        const int* __restrict__ row = nbr + (size_t)v * (size_t)maxdeg;

        int my = (v < n) ? 0 : 2;
        for (;; ++r) {
            if (t == 0) F[(r + 1) % 3] = 0;
            if (my == 0) {
                if (st[v] != 0) { my = 2; }
                else {
                    bool anyH = false; int undec = 0;
                    if (!ovf) {
                        if (np > 0) { int s = st[b + e0]; anyH |= (s == 1); undec += (s == 0); }
                        if (np > 1) { int s = st[b + e1]; anyH |= (s == 1); undec += (s == 0); }
                        if (np > 2) { int s = st[b + e2]; anyH |= (s == 1); undec += (s == 0); }
                        if (np > 3) { int s = st[b + e3]; anyH |= (s == 1); undec += (s == 0); }
                        if (np > 4) { int s = st[b + e4]; anyH |= (s == 1); undec += (s == 0); }
                        if (np > 5) { int s = st[b + e5]; anyH |= (s == 1); undec += (s == 0); }
                        if (np > 6) { int s = st[b + e6]; anyH |= (s == 1); undec += (s == 0); }
                    } else {
                        for (int k = 0; k < dv; ++k) {
                            int j = row[k];
                            if (j >= b && j < v) {
                                int s = st[j];
                                anyH |= (s == 1); undec += (s == 0);
                            }
                        }
                    }
                    if (anyH) { my = 2; }
                    else if (undec == 0) {
                        my = 1;
                        st[v] = 1;
                        // push: every higher neighbor of a head is non-head
                        for (int k = 0; k < dv; ++k) {
                            int j = row[k];
                            if (j > v) st[j] = 2;
                        }
                    }
                }
                if (my == 0) F[r % 3] = 1;
            }
            __syncthreads();
            if (F[r % 3] == 0) { ++r; break; }
        }
        pv = pnx; dv = dnx;
    }

    // ---- head rank prefix sum (index order), shfl-based ----
    const int base = t * (NV / 1024);           // 16 consecutive vertices/thread
    int cnt = 0;
    #pragma unroll
    for (int i = 0; i < NV / 1024; ++i) {
        int v = base + i;
        cnt += (v < n && st[v] == 1) ? 1 : 0;
    }
    int c = cnt;
    #pragma unroll
    for (int off = 1; off < 64; off <<= 1) {
        int x = __shfl_up(c, off);
        if (lane >= off) c += x;
    }
    if (lane == 63) s_ws[wid] = c;
    __syncthreads();
    int wexcl = 0, tot = 0;
    #pragma unroll
    for (int w = 0; w < 16; ++w) {
        int s = s_ws[w];
        tot += s;
        if (w < wid) wexcl += s;
    }
    int excl = wexcl + (c - cnt);
    #pragma unroll
    for (int i = 0; i < NV / 1024; ++i) {
        int v = base + i;
        if (v < n) {
            bool h = (st[v] == 1);
            g_rank[v] = h ? excl : -1;
            excl += h ? 1 : 0;
        }
    }
    for (int i = t; i < n; i += 1024)
        out_tail[i] = (st[i] == 1) ? 1.0f : 0.0f;   // head_mask, coalesced
    if (t == 0) out_tail[n] = (float)tot;           // num_clusters
}

// ---------------------------------------------------------------------------
// K2: owner[v] = v if head, else min-index head neighbor (always exists, < v).
// ---------------------------------------------------------------------------
__global__ __launch_bounds__(256)
void k_owner(const int* __restrict__ nbr, const int* __restrict__ deg,
             int maxdeg, int n,
             const int* __restrict__ g_rank, int* __restrict__ owner)
{
    int v = blockIdx.x * 256 + threadIdx.x;
    if (v >= n) return;
    if (g_rank[v] >= 0) { owner[v] = v; return; }
    const int* __restrict__ row = nbr + (size_t)v * (size_t)maxdeg;
    const int dv = deg[v];
    int mn = 0x7fffffff;
    for (int k = 0; k < dv; ++k) {
        int j = row[k];
        if (g_rank[j] >= 0 && j < mn) mn = j;
    }
    owner[v] = mn;
}

// ---------------------------------------------------------------------------
// K3: one 64-lane wave per vertex; head waves compute the cluster mean.
// Members of head h = {h} U { j in nbr[h] : owner[j] == h }.
// Row layout: 256 floats = 64 lanes x float4, fully coalesced per row.
// ---------------------------------------------------------------------------
__global__ __launch_bounds__(256)
void k_avg(const float* __restrict__ vert, const int* __restrict__ nbr,
           const int* __restrict__ deg, int maxdeg, int n,
           const int* __restrict__ g_rank, const int* __restrict__ owner,
           float* __restrict__ out)
{
    const int wid  = (blockIdx.x * 256 + threadIdx.x) >> 6;
    const int lane = threadIdx.x & 63;
    if (wid >= n) return;
    const int h = wid;
    const int c = g_rank[h];
    if (c < 0) return;                       // not a head

    const int dh = deg[h];
    const int* __restrict__ row = nbr + (size_t)h * (size_t)maxdeg;

    float4 acc = reinterpret_cast<const float4*>(vert + (size_t)h * DD)[lane];
    int cnt = 1;

    for (int k0 = 0; k0 < dh; k0 += 64) {
        int k = k0 + lane;
        int j = (k < dh) ? row[k] : -1;
        bool mem = (j >= 0) && (owner[j] == h);
        unsigned long long m = __ballot(mem);
        cnt += __popcll(m);
        while (m) {
            int bit = __ffsll((long long)m) - 1;
            m &= (m - 1);
            int jj = __shfl(j, bit);
            float4 rr = reinterpret_cast<const float4*>(vert + (size_t)jj * DD)[lane];
            acc.x += rr.x; acc.y += rr.y; acc.z += rr.z; acc.w += rr.w;
        }
    }
    const float inv = 1.0f / (float)cnt;
    float4 res;
    res.x = acc.x * inv; res.y = acc.y * inv;
    res.z = acc.z * inv; res.w = acc.w * inv;
    reinterpret_cast<float4*>(out + (size_t)c * DD)[lane] = res;
}

// ---------------------------------------------------------------------------
extern "C" void kernel_launch(void* const* d_in, const int* in_sizes, int n_in,
                              void* d_out, int out_size, void* d_ws, size_t ws_size,
                              hipStream_t stream)
{
    const float* vert = (const float*)d_in[0];
    const int*   nbr  = (const int*)d_in[1];
    const int*   deg  = (const int*)d_in[2];

    const int n      = in_sizes[2];            // 16384
    const int maxdeg = in_sizes[1] / n;
    const int d      = in_sizes[0] / n;        // 256

    int*   owner  = (int*)d_ws;                              // n ints
    int*   rank   = owner + n;                               // n ints
    uint4* pend_g = (uint4*)((char*)d_ws + 2 * (size_t)n * sizeof(int)); // n uint4
    float* out      = (float*)d_out;
    float* out_tail = out + (size_t)n * (size_t)d;   // head_mask .. num_clusters

    // rows >= num_clusters must be zero; also covers the tail before K1 writes it
    hipMemsetAsync(d_out, 0, (size_t)out_size * sizeof(float), stream);

    hipLaunchKernelGGL(k_prep, dim3((n + 255) / 256), dim3(256), 0, stream,
                       nbr, deg, maxdeg, n, pend_g);

    hipLaunchKernelGGL(k_mis, dim3(1), dim3(1024), 0, stream,
                       nbr, deg, maxdeg, n, pend_g, rank, out_tail);

    hipLaunchKernelGGL(k_owner, dim3((n + 255) / 256), dim3(256), 0, stream,
                       nbr, deg, maxdeg, n, rank, owner);

    const int blocks = (n * 64 + 255) / 256;   // one wave per vertex
    hipLaunchKernelGGL(k_avg, dim3(blocks), dim3(256), 0, stream,
                       vert, nbr, deg, maxdeg, n, rank, owner, out);
}

// Round 4
// 89.081 us; speedup vs baseline: 3.7261x; 1.5627x over previous
//
#include <hip/hip_runtime.h>
#include <cstdint>
#include <cstddef>

// Problem constants (from reference): N=16384, D=256.
#define NV 16384
#define DD 256
#define BLK 1024
#define PCAP 7
#define HROW 24   // u16 slots per vertex in hi_g: [0]=count, [1..23]=higher nbrs

// ---------------------------------------------------------------------------
// K_prep (parallel, one pass over nbr): per vertex v emit
//  - pend_g[v] (uint4): in-block lower neighbors as u16 offsets
//      x = count | e0<<16 ; y = e1|e2<<16 ; z = e3|e4<<16 ; w = e5|e6<<16
//  - hi_g[v*24..]: [count, up to 23 higher-neighbor vertex ids] (u16)
// Both are status-independent; they are the only graph data k_mis needs.
// ---------------------------------------------------------------------------
__global__ __launch_bounds__(256)
void k_prep(const int* __restrict__ nbr, const int* __restrict__ deg,
            int maxdeg, int n, uint4* __restrict__ pend_g,
            unsigned short* __restrict__ hi_g)
{
    int v = blockIdx.x * 256 + threadIdx.x;
    if (v >= n) return;
    const int b  = v & ~(BLK - 1);
    const int dv = deg[v];
    const int* __restrict__ row = nbr + (size_t)v * (size_t)maxdeg;
    unsigned short* __restrict__ hrow = hi_g + (size_t)v * HROW;
    unsigned w0 = 0, w1 = 0, w2 = 0, w3 = 0;
    int cnt = 0, hic = 0;
    for (int k = 0; k < dv; ++k) {
        int j = row[k];
        if (j > v) {
            if (hic < HROW - 1) hrow[1 + hic] = (unsigned short)j;
            ++hic;
        } else if (j >= b) {
            unsigned val = (unsigned)(j - b);
            switch (cnt) {
                case 0: w0 |= val << 16; break;
                case 1: w1 |= val;       break;
                case 2: w1 |= val << 16; break;
                case 3: w2 |= val;       break;
                case 4: w2 |= val << 16; break;
                case 5: w3 |= val;       break;
                case 6: w3 |= val << 16; break;
                default: break;
            }
            ++cnt;
        }
    }
    hrow[0] = (unsigned short)hic;
    w0 |= (unsigned)(cnt > 0xffff ? 0xffff : cnt);
    uint4 p; p.x = w0; p.y = w1; p.z = w2; p.w = w3;
    pend_g[v] = p;
}

// ---------------------------------------------------------------------------
// K_mis: lexicographic greedy MIS, single WG, push model.
// st: 0=unknown, 1=head, 2=nonhead (monotone -> LDS races benign).
// Heads push st=2 to higher neighbors from REGISTER-resident hi lists.
// 3 decision passes per barrier (monotone LDS writes visible intra-WG)
// collapse ~3 dependency levels per round.
// ---------------------------------------------------------------------------
__global__ __launch_bounds__(1024)
void k_mis(const int* __restrict__ nbr, const int* __restrict__ deg,
           int maxdeg, int n,
           const uint4* __restrict__ pend_g, const unsigned short* __restrict__ hi_g,
           int* __restrict__ headlist, float* __restrict__ out_tail)
{
    __shared__ __align__(16) unsigned char st[NV];
    __shared__ int s_ws[16];
    __shared__ int F[3];
    const int t    = threadIdx.x;
    const int lane = t & 63;
    const int wid  = t >> 6;

    ((uint4*)st)[t] = make_uint4(0u, 0u, 0u, 0u);   // 1024*16B == NV
    if (t < 3) F[t] = 0;
    __syncthreads();

    // prefetch block 0 (pend + hi row + deg), register double-buffered
    uint4 pv = make_uint4(0,0,0,0), h0 = pv, h1 = pv, h2 = pv;
    int   dv = 0;
    if (t < n) {
        pv = pend_g[t];
        const uint4* hp = (const uint4*)(hi_g + (size_t)t * HROW);
        h0 = hp[0]; h1 = hp[1]; h2 = hp[2];
        dv = deg[t];
    }
    int r = 0;

    for (int b = 0; b < n; b += BLK) {
        const int v = b + t;
        // prefetch next block while this one iterates
        uint4 pn = make_uint4(0,0,0,0), n0 = pn, n1 = pn, n2 = pn;
        int   dn = 0;
        {
            int vn = b + BLK + t;
            if (vn < n) {
                pn = pend_g[vn];
                const uint4* hp = (const uint4*)(hi_g + (size_t)vn * HROW);
                n0 = hp[0]; n1 = hp[1]; n2 = hp[2];
                dn = deg[vn];
            }
        }

        const int np = pv.x & 0xffff;
        const int e0 = pv.x >> 16,    e1 = pv.y & 0xffff, e2 = pv.y >> 16;
        const int e3 = pv.z & 0xffff, e4 = pv.z >> 16;
        const int e5 = pv.w & 0xffff, e6 = pv.w >> 16;
        const int hic = (int)(h0.x & 0xffff);
        const int* __restrict__ row = nbr + (size_t)v * (size_t)maxdeg;

        int my = (v < n) ? 0 : 2;
        for (;; ++r) {
            if (t == 0) F[(r + 1) % 3] = 0;
            #pragma unroll
            for (int pass = 0; pass < 3; ++pass) {
                if (my == 0) {
                    if (st[v] != 0) { my = 2; }
                    else {
                        bool anyH = false; int undec = 0;
                        if (np <= PCAP) {
                            if (np > 0) { int s = st[b + e0]; anyH |= (s == 1); undec += (s == 0); }
                            if (np > 1) { int s = st[b + e1]; anyH |= (s == 1); undec += (s == 0); }
                            if (np > 2) { int s = st[b + e2]; anyH |= (s == 1); undec += (s == 0); }
                            if (np > 3) { int s = st[b + e3]; anyH |= (s == 1); undec += (s == 0); }
                            if (np > 4) { int s = st[b + e4]; anyH |= (s == 1); undec += (s == 0); }
                            if (np > 5) { int s = st[b + e5]; anyH |= (s == 1); undec += (s == 0); }
                            if (np > 6) { int s = st[b + e6]; anyH |= (s == 1); undec += (s == 0); }
                        } else {
                            for (int k = 0; k < dv; ++k) {
                                int j = row[k];
                                if (j >= b && j < v) {
                                    int s = st[j];
                                    anyH |= (s == 1); undec += (s == 0);
                                }
                            }
                        }
                        if (anyH) { my = 2; }
                        else if (undec == 0) {
                            my = 1;
                            st[v] = 1;
                            if (hic <= HROW - 1) {
                                // push from registers: entry i (0-based) at u16 slot 1+i
                                #define PUSHE(word, sh, i) if ((i) < hic) st[((word) >> (sh)) & 0xffffu] = 2
                                PUSHE(h0.x,16, 0); PUSHE(h0.y, 0, 1); PUSHE(h0.y,16, 2);
                                PUSHE(h0.z, 0, 3); PUSHE(h0.z,16, 4); PUSHE(h0.w, 0, 5);
                                PUSHE(h0.w,16, 6);
                                PUSHE(h1.x, 0, 7); PUSHE(h1.x,16, 8); PUSHE(h1.y, 0, 9);
                                PUSHE(h1.y,16,10); PUSHE(h1.z, 0,11); PUSHE(h1.z,16,12);
                                PUSHE(h1.w, 0,13); PUSHE(h1.w,16,14);
                                PUSHE(h2.x, 0,15); PUSHE(h2.x,16,16); PUSHE(h2.y, 0,17);
                                PUSHE(h2.y,16,18); PUSHE(h2.z, 0,19); PUSHE(h2.z,16,20);
                                PUSHE(h2.w, 0,21); PUSHE(h2.w,16,22);
                                #undef PUSHE
                            } else {
                                for (int k = 0; k < dv; ++k) {
                                    int j = row[k];
                                    if (j > v) st[j] = 2;
                                }
                            }
                        }
                    }
                }
            }
            if (my == 0) F[r % 3] = 1;
            __syncthreads();
            if (F[r % 3] == 0) { ++r; break; }
        }
        pv = pn; h0 = n0; h1 = n1; h2 = n2; dv = dn;
    }

    // ---- head rank prefix sum (index order), shfl-based ----
    const int base = t * (NV / 1024);           // 16 consecutive vertices/thread
    int cnt = 0;
    #pragma unroll
    for (int i = 0; i < NV / 1024; ++i) {
        int v = base + i;
        cnt += (v < n && st[v] == 1) ? 1 : 0;
    }
    int c = cnt;
    #pragma unroll
    for (int off = 1; off < 64; off <<= 1) {
        int x = __shfl_up(c, off);
        if (lane >= off) c += x;
    }
    if (lane == 63) s_ws[wid] = c;
    __syncthreads();
    int wexcl = 0, tot = 0;
    #pragma unroll
    for (int w = 0; w < 16; ++w) {
        int s = s_ws[w];
        tot += s;
        if (w < wid) wexcl += s;
    }
    int excl = wexcl + (c - cnt);
    #pragma unroll
    for (int i = 0; i < NV / 1024; ++i) {
        int v = base + i;
        if (v < n && st[v] == 1) { headlist[excl] = v; ++excl; }
    }
    for (int i = t; i < n; i += 1024)
        out_tail[i] = (st[i] == 1) ? 1.0f : 0.0f;   // head_mask, coalesced
    if (t == 0) out_tail[n] = (float)tot;           // num_clusters
}

// ---------------------------------------------------------------------------
// K_owner: 16 lanes per vertex. owner[v] = v if head else min head neighbor.
// Head test via head_mask floats (in d_out, written by k_mis).
// ---------------------------------------------------------------------------
__global__ __launch_bounds__(256)
void k_owner(const int* __restrict__ nbr, const int* __restrict__ deg,
             int maxdeg, int n,
             const float* __restrict__ hm, int* __restrict__ owner)
{
    int gid = blockIdx.x * 256 + threadIdx.x;
    int v = gid >> 4, l = gid & 15;
    if (v >= n) return;
    if (hm[v] != 0.0f) { if (l == 0) owner[v] = v; return; }
    const int* __restrict__ row = nbr + (size_t)v * (size_t)maxdeg;
    const int dv = deg[v];
    int mn = 0x7fffffff;
    for (int k = l; k < dv; k += 16) {
        int j = row[k];
        if (hm[j] != 0.0f) mn = min(mn, j);
    }
    #pragma unroll
    for (int off = 8; off; off >>= 1) mn = min(mn, __shfl_xor(mn, off, 16));
    if (l == 0) owner[v] = mn;
}

// ---------------------------------------------------------------------------
// K_avg: one 64-lane wave per cluster slot; wave c handles head headlist[c].
// Members of head h = {h} U { j in nbr[h] : owner[j] == h }.
// ---------------------------------------------------------------------------
__global__ __launch_bounds__(256)
void k_avg(const float* __restrict__ vert, const int* __restrict__ nbr,
           const int* __restrict__ deg, int maxdeg, int n,
           const int* __restrict__ headlist, const int* __restrict__ owner,
           const float* __restrict__ tail, float* __restrict__ out)
{
    const int w    = (blockIdx.x * 256 + threadIdx.x) >> 6;
    const int lane = threadIdx.x & 63;
    const int tot  = (int)tail[n];
    if (w >= tot) return;
    const int h = headlist[w];

    const int dh = deg[h];
    const int* __restrict__ row = nbr + (size_t)h * (size_t)maxdeg;

    float4 acc = reinterpret_cast<const float4*>(vert + (size_t)h * DD)[lane];
    int cnt = 1;

    for (int k0 = 0; k0 < dh; k0 += 64) {
        int k = k0 + lane;
        int j = (k < dh) ? row[k] : -1;
        bool mem = (j >= 0) && (owner[j] == h);
        unsigned long long m = __ballot(mem);
        cnt += __popcll(m);
        while (m) {
            int bit = __ffsll((long long)m) - 1;
            m &= (m - 1);
            int jj = __shfl(j, bit);
            float4 rr = reinterpret_cast<const float4*>(vert + (size_t)jj * DD)[lane];
            acc.x += rr.x; acc.y += rr.y; acc.z += rr.z; acc.w += rr.w;
        }
    }
    const float inv = 1.0f / (float)cnt;
    float4 res;
    res.x = acc.x * inv; res.y = acc.y * inv;
    res.z = acc.z * inv; res.w = acc.w * inv;
    reinterpret_cast<float4*>(out + (size_t)w * DD)[lane] = res;
}

// ---------------------------------------------------------------------------
extern "C" void kernel_launch(void* const* d_in, const int* in_sizes, int n_in,
                              void* d_out, int out_size, void* d_ws, size_t ws_size,
                              hipStream_t stream)
{
    const float* vert = (const float*)d_in[0];
    const int*   nbr  = (const int*)d_in[1];
    const int*   deg  = (const int*)d_in[2];

    const int n      = in_sizes[2];            // 16384
    const int maxdeg = in_sizes[1] / n;
    const int d      = in_sizes[0] / n;        // 256

    int*   owner    = (int*)d_ws;                                  // n ints
    int*   headlist = owner + n;                                   // n ints
    uint4* pend_g   = (uint4*)(headlist + n);                      // n uint4 (2n ints offset: 16B aligned)
    unsigned short* hi_g = (unsigned short*)(pend_g + n);          // n * HROW u16

    float* out      = (float*)d_out;
    float* out_tail = out + (size_t)n * (size_t)d;   // head_mask .. num_clusters

    // rows >= num_clusters must be zero
    hipMemsetAsync(d_out, 0, (size_t)out_size * sizeof(float), stream);

    hipLaunchKernelGGL(k_prep, dim3((n + 255) / 256), dim3(256), 0, stream,
                       nbr, deg, maxdeg, n, pend_g, hi_g);

    hipLaunchKernelGGL(k_mis, dim3(1), dim3(1024), 0, stream,
                       nbr, deg, maxdeg, n, pend_g, hi_g, headlist, out_tail);

    hipLaunchKernelGGL(k_owner, dim3((n * 16 + 255) / 256), dim3(256), 0, stream,
                       nbr, deg, maxdeg, n, out_tail, owner);

    const int blocks = (n * 64 + 255) / 256;   // one wave per potential cluster
    hipLaunchKernelGGL(k_avg, dim3(blocks), dim3(256), 0, stream,
                       vert, nbr, deg, maxdeg, n, headlist, owner, out_tail, out);
}